// Round 3
// baseline (482.738 us; speedup 1.0000x reference)
//
#include <hip/hip_runtime.h>
#include <math.h>

#define BATCH   131072
#define OUTD    700
#define H1D     25
#define H2D     20

// workspace layout (doubles at offset 0):
//   [0,50)    w1d      (W1 as f64, 2x25)
//   [50,75)   b1d
//   [75,575)  w2d      (25x20)
//   [575,595) b2d
//   [595,675) cgd[q][k] reduced trapz weights
//   [675,679) cbd[q]
// byte 8192:  h2f  (BATCH*20 f32, 10.5 MB)
// byte 8192+10485760: scl (BATCH float4, 2 MB)
#define P_N 679

// ---------------- K0: one-block setup (bit-identical to R2 per-block setup) ----
__global__ __launch_bounds__(256) void setup_kernel(
    const float* __restrict__ W1, const float* __restrict__ b1,
    const float* __restrict__ W2, const float* __restrict__ b2,
    const float* __restrict__ W3, const float* __restrict__ b3,
    double* __restrict__ P)
{
    __shared__ float  xgs[50];
    __shared__ double cwd[50];
    const int t = threadIdx.x;

    if (t < 50) {
        // match np.logspace(-7,0,50).astype(float32); volatile blocks fma
        volatile double m = (double)t * (7.0 / 49.0);
        double e = m + (-7.0);
        xgs[t] = (t == 49) ? 1.0f : (float)pow(10.0, e);
    }
    __syncthreads();
    if (t < 50) {
        float xp = (t < 49) ? xgs[t + 1] : xgs[t];
        float xm = (t > 0)  ? xgs[t - 1] : xgs[t];
        cwd[t] = 0.5 * ((double)xp - (double)xm);
    }
    __syncthreads();

    if (t < 2 * H1D) P[t] = (double)W1[t];
    if (t < H1D)     P[50 + t] = (double)b1[t];
    for (int i = t; i < H1D * H2D; i += 256) P[75 + i] = (double)W2[i];
    if (t < H2D)     P[575 + t] = (double)b2[t];

    if (t < 4 * H2D) {
        const int q = t / H2D, k = t % H2D;
        const float* col = W3 + k * OUTD;
        double acc = 0.0;
        if (q == 0) {
            for (int i = 0; i < 50; ++i)
                acc = fma(cwd[i], (double)col[50 + i] + (double)col[100 + i], acc);
        } else {
            const int off = 100 + 50 * q;
            for (int i = 0; i < 50; ++i)
                acc = fma(cwd[i], (double)col[off + i], acc);
        }
        P[595 + t] = acc;   // cgd[q][k], t = q*20+k
    }
    if (t < 4) {
        const int q = t;
        double acc = 0.0;
        if (q == 0) {
            for (int i = 0; i < 50; ++i)
                acc = fma(cwd[i], (double)b3[50 + i] + (double)b3[100 + i], acc);
        } else {
            const int off = 100 + 50 * q;
            for (int i = 0; i < 50; ++i)
                acc = fma(cwd[i], (double)b3[off + i], acc);
        }
        P[675 + q] = acc;
    }
}

// ---------------- K1: per-sample f64 front-end (FROZEN arithmetic) ----------
#define K1_BLK  256
#define K1_NBLK (BATCH / K1_BLK)   // 512

__global__ __launch_bounds__(K1_BLK) void frontend_kernel(
    const float* __restrict__ x, const double* __restrict__ P,
    float* __restrict__ h2f_out, float4* __restrict__ scl_out)
{
    __shared__ double L[P_N];
    const int t = threadIdx.x;
    for (int i = t; i < P_N; i += K1_BLK) L[i] = P[i];
    __syncthreads();

    const double* w1d = L;
    const double* b1d = L + 50;
    const double* w2d = L + 75;
    const double* b2d = L + 575;
    const double* cgd = L + 595;   // [q*20+k]
    const double* cbd = L + 675;

    const int sid = blockIdx.x * K1_BLK + t;
    const float2 xv = ((const float2*)x)[sid];
    const double x0 = (double)xv.x;
    const double x1 = (double)xv.y;

    double h1[H1D];
    #pragma unroll
    for (int k = 0; k < H1D; ++k)
        h1[k] = tanh(fma(x0, w1d[k], fma(x1, w1d[H1D + k], b1d[k])));

    double h2[H2D];
    #pragma unroll
    for (int m = 0; m < H2D; ++m) {
        double acc = b2d[m];
        #pragma unroll
        for (int k = 0; k < H1D; ++k) acc = fma(h1[k], w2d[k * H2D + m], acc);
        h2[m] = tanh(acc);
    }

    float4 sv;
    float* svp = (float*)&sv;
    #pragma unroll
    for (int q = 0; q < 4; ++q) {
        double acc = cbd[q];
        #pragma unroll
        for (int k = 0; k < H2D; ++k) acc = fma(h2[k], cgd[q * H2D + k], acc);
        const double num = (q & 1) ? 3.0 : 1.0;   // 1/g, 3/v, 1/v3, 3/v8
        svp[q] = (float)(num / acc);
    }

    float4* h2o = (float4*)(h2f_out + (size_t)sid * H2D);
    #pragma unroll
    for (int q5 = 0; q5 < 5; ++q5) {
        float4 v;
        v.x = (float)h2[4 * q5 + 0]; v.y = (float)h2[4 * q5 + 1];
        v.z = (float)h2[4 * q5 + 2]; v.w = (float)h2[4 * q5 + 3];
        h2o[q5] = v;
    }
    scl_out[sid] = sv;
}

// ---------------- K2: fp32 back-end GEMM + scale + store (no LDS) ----------
#define K2_BLK  256
#define K2_SPB  64                     // samples per block
#define K2_NBLK (BATCH / K2_SPB)       // 2048

__global__ __launch_bounds__(K2_BLK) void backend_kernel(
    const float* __restrict__ h2f_in, const float4* __restrict__ scl_in,
    const float* __restrict__ W3, const float* __restrict__ b3,
    float* __restrict__ out)
{
    const int t = threadIdx.x;

    // W3 columns into registers: thread t owns columns t, t+256, t+512
    float w3r[3][H2D];
    float b3r[3];
    int   bkt[3];
    #pragma unroll
    for (int c = 0; c < 3; ++c) {
        const int j = t + K2_BLK * c;
        if (j < OUTD) {
            b3r[c] = b3[j];
            #pragma unroll
            for (int k = 0; k < H2D; ++k) w3r[c][k] = W3[k * OUTD + j];
        } else {
            b3r[c] = 0.0f;
            #pragma unroll
            for (int k = 0; k < H2D; ++k) w3r[c][k] = 0.0f;
        }
        int b = 0;
        if      (j >= 50  && j < 150) b = 1;
        else if (j >= 150 && j < 200) b = 2;
        else if (j >= 200 && j < 250) b = 3;
        else if (j >= 250 && j < 300) b = 4;
        bkt[c] = b;
    }

    const int s0 = blockIdx.x * K2_SPB;
    const float*  hp   = h2f_in + (size_t)s0 * H2D;   // uniform → scalar loads
    const float4* sp   = scl_in + s0;                 // uniform → scalar loads
    float*        outp = out + (size_t)s0 * OUTD;

    for (int s = 0; s < K2_SPB; ++s) {
        float h[H2D];
        #pragma unroll
        for (int q5 = 0; q5 < 5; ++q5) {
            const float4 hv = ((const float4*)hp)[q5];
            h[4 * q5 + 0] = hv.x; h[4 * q5 + 1] = hv.y;
            h[4 * q5 + 2] = hv.z; h[4 * q5 + 3] = hv.w;
        }
        const float4 sv = *sp;

        #pragma unroll
        for (int c = 0; c < 3; ++c) {
            const int j = t + K2_BLK * c;
            if (j < OUTD) {
                float acc = b3r[c];
                #pragma unroll
                for (int k = 0; k < H2D; ++k) acc = fmaf(h[k], w3r[c][k], acc);
                float sc = 1.0f;
                if      (bkt[c] == 1) sc = sv.x;
                else if (bkt[c] == 2) sc = sv.y;
                else if (bkt[c] == 3) sc = sv.z;
                else if (bkt[c] == 4) sc = sv.w;
                outp[j] = acc * sc;
            }
        }
        hp   += H2D;
        sp   += 1;
        outp += OUTD;
    }
}

extern "C" void kernel_launch(void* const* d_in, const int* in_sizes, int n_in,
                              void* d_out, int out_size, void* d_ws, size_t ws_size,
                              hipStream_t stream) {
    const float* x  = (const float*)d_in[0];
    const float* W1 = (const float*)d_in[1];
    const float* b1 = (const float*)d_in[2];
    const float* W2 = (const float*)d_in[3];
    const float* b2 = (const float*)d_in[4];
    const float* W3 = (const float*)d_in[5];
    const float* b3 = (const float*)d_in[6];
    float* out = (float*)d_out;

    double* P   = (double*)d_ws;
    float*  h2f = (float*)((char*)d_ws + 8192);
    float4* scl = (float4*)((char*)d_ws + 8192 + (size_t)BATCH * H2D * 4);

    hipLaunchKernelGGL(setup_kernel, dim3(1), dim3(256), 0, stream,
                       W1, b1, W2, b2, W3, b3, P);
    hipLaunchKernelGGL(frontend_kernel, dim3(K1_NBLK), dim3(K1_BLK), 0, stream,
                       x, P, h2f, scl);
    hipLaunchKernelGGL(backend_kernel, dim3(K2_NBLK), dim3(K2_BLK), 0, stream,
                       h2f, scl, W3, b3, out);
}